// Round 1
// baseline (1514.551 us; speedup 1.0000x reference)
//
#include <hip/hip_runtime.h>
#include <hip/hip_bf16.h>
#include <math.h>

#define HID 64
#define NPB 4  // nodes per block in the fused gate kernel

// ---------------- degree (counts of src occurrences) ----------------
__global__ void deg_kernel(const int* __restrict__ ei, int E, float* __restrict__ deg) {
    int e = blockIdx.x * blockDim.x + threadIdx.x;
    if (e < E) {
        atomicAdd(&deg[ei[e]], 1.0f);
    }
}

__global__ void dinv_kernel(const float* __restrict__ deg, float* __restrict__ dinv, int N) {
    int n = blockIdx.x * blockDim.x + threadIdx.x;
    if (n < N) {
        float dg = deg[n];
        dinv[n] = dg > 0.0f ? rsqrtf(fmaxf(dg, 1.0f)) : 0.0f;
    }
}

// ---------------- 2-channel propagation (input path) ----------------
__global__ void prop2_kernel(const int* __restrict__ ei, int E,
                             const float* __restrict__ dinv,
                             const float* __restrict__ src, float* __restrict__ dst, int N) {
    int e = blockIdx.x * blockDim.x + threadIdx.x;
    if (e < E) {
        int s = ei[e], d = ei[E + e];
        if ((unsigned)s < (unsigned)N && (unsigned)d < (unsigned)N) {
            float nw = -dinv[s] * dinv[d];
            float v0 = src[2*s], v1 = src[2*s + 1];
            atomicAdd(&dst[2*d],     nw * v0);
            atomicAdd(&dst[2*d + 1], nw * v1);
        }
    }
}

// ---------------- 64-channel propagation (hidden path) ----------------
// One edge per 64-lane group: lane = channel. Gather and scatter both coalesced.
__global__ void prop64_kernel(const int* __restrict__ ei, int E,
                              const float* __restrict__ dinv,
                              const float* __restrict__ src, float* __restrict__ dst, int N) {
    long long idx = (long long)blockIdx.x * blockDim.x + threadIdx.x;
    int e = (int)(idx >> 6);
    int c = threadIdx.x & 63;
    if (e < E) {
        int s = ei[e], d = ei[E + e];
        if ((unsigned)s < (unsigned)N && (unsigned)d < (unsigned)N) {
            float nw = -dinv[s] * dinv[d];
            atomicAdd(&dst[d * HID + c], nw * src[s * HID + c]);
        }
    }
}

// ---------------- input conv: out = b1 + Tx0@W1[0] + Tx1@W1[1] + Tx2@W1[2] ----
// Tx2 folded: tx2 = 2*txb - x.  W1 layout [3][2][64].
__global__ void input_conv_kernel(const float* __restrict__ x,
                                  const float* __restrict__ txa,
                                  const float* __restrict__ txb,
                                  const float* __restrict__ W1, const float* __restrict__ b1,
                                  float* __restrict__ out, int N) {
    int idx = blockIdx.x * blockDim.x + threadIdx.x;
    if (idx < N * HID) {
        int n = idx >> 6, j = idx & 63;
        float x0 = x[2*n], x1 = x[2*n + 1];
        float t10 = txa[2*n], t11 = txa[2*n + 1];
        float t20 = 2.0f * txb[2*n] - x0, t21 = 2.0f * txb[2*n + 1] - x1;
        float o = b1[j]
                + x0  * W1[j]        + x1  * W1[64 + j]
                + t10 * W1[128 + j]  + t11 * W1[192 + j]
                + t20 * W1[256 + j]  + t21 * W1[320 + j];
        out[idx] = o;
    }
}

// ---------------- fused hidden_conv + GRU gates ----------------
// block = NPB nodes x 64 lanes. hidden_conv computed in-LDS (never hits global).
// d_out holds input_conv on entry; overwritten with final output (reads staged
// into LDS before the first barrier, writes after — safe).
__global__ void gate_kernel(float* __restrict__ out,            // in: input_conv, out: result
                            const float* __restrict__ h,
                            const float* __restrict__ tx1,      // bufA = prop(h)
                            const float* __restrict__ pp,       // bufB = prop(prop(h))
                            const float* __restrict__ W2, const float* __restrict__ b2,
                            const float* __restrict__ Wz, const float* __restrict__ bz,
                            const float* __restrict__ Wr, const float* __restrict__ br,
                            const float* __restrict__ Wc, const float* __restrict__ bc,
                            int N) {
    __shared__ float s_ic[NPB][HID];
    __shared__ float s_h [NPB][HID];
    __shared__ float s_t1[NPB][HID];
    __shared__ float s_t2[NPB][HID];
    __shared__ float s_hc[NPB][HID];
    __shared__ float s_r [NPB][HID];

    int ln = threadIdx.x >> 6;       // node-in-block
    int j  = threadIdx.x & 63;       // output channel
    int n  = blockIdx.x * NPB + ln;
    bool act = (n < N);
    int base = act ? n * HID : 0;

    float hj = h[base + j];
    s_ic[ln][j] = out[base + j];
    s_h [ln][j] = hj;
    s_t1[ln][j] = tx1[base + j];
    s_t2[ln][j] = 2.0f * pp[base + j] - hj;   // Tx2 = 2*prop(Tx1) - h
    __syncthreads();

    // hidden_conv_j = b2[j] + sum_i h_i*W2[0][i][j] + t1_i*W2[1][i][j] + t2_i*W2[2][i][j]
    float acc = b2[j];
    #pragma unroll 8
    for (int i = 0; i < HID; ++i) {
        acc += s_h [ln][i] * W2[i * 64 + j]
             + s_t1[ln][i] * W2[4096 + i * 64 + j]
             + s_t2[ln][i] * W2[8192 + i * 64 + j];
    }
    s_hc[ln][j] = acc;
    __syncthreads();

    // z, r gates: combined = [ic, hc]
    float az = bz[j], ar = br[j];
    #pragma unroll 8
    for (int i = 0; i < HID; ++i) {
        float c = s_ic[ln][i];
        az += c * Wz[i * 64 + j];
        ar += c * Wr[i * 64 + j];
    }
    #pragma unroll 8
    for (int i = 0; i < HID; ++i) {
        float c = s_hc[ln][i];
        az += c * Wz[(64 + i) * 64 + j];
        ar += c * Wr[(64 + i) * 64 + j];
    }
    float z = 1.0f / (1.0f + expf(-az));
    float r = 1.0f / (1.0f + expf(-ar));
    s_r[ln][j] = r;
    __syncthreads();

    // candidate: comb_c = [ic, r*hc]
    float ac = bc[j];
    #pragma unroll 8
    for (int i = 0; i < HID; ++i) {
        ac += s_ic[ln][i] * Wc[i * 64 + j];
    }
    #pragma unroll 8
    for (int i = 0; i < HID; ++i) {
        ac += s_r[ln][i] * s_hc[ln][i] * Wc[(64 + i) * 64 + j];
    }
    float ht = tanhf(ac);

    if (act) out[base + j] = z * hj + (1.0f - z) * ht;
}

extern "C" void kernel_launch(void* const* d_in, const int* in_sizes, int n_in,
                              void* d_out, int out_size, void* d_ws, size_t ws_size,
                              hipStream_t stream) {
    const float* x  = (const float*)d_in[0];
    const int*   ei = (const int*)  d_in[1];
    const float* h  = (const float*)d_in[2];
    const float* W1 = (const float*)d_in[3];
    const float* b1 = (const float*)d_in[4];
    const float* W2 = (const float*)d_in[5];
    const float* b2 = (const float*)d_in[6];
    const float* Wz = (const float*)d_in[7];
    const float* bz = (const float*)d_in[8];
    const float* Wr = (const float*)d_in[9];
    const float* br = (const float*)d_in[10];
    const float* Wc = (const float*)d_in[11];
    const float* bc = (const float*)d_in[12];
    float* out = (float*)d_out;

    int N = in_sizes[0] / 2;     // 100000
    int E = in_sizes[1] / 2;     // 1600000

    // workspace layout (floats): [deg N][txa 2N][txb 2N][bufA 64N][bufB 64N][dinv N]
    float* ws   = (float*)d_ws;
    float* deg  = ws;
    float* txa  = ws + (size_t)N;
    float* txb  = ws + (size_t)3 * N;
    float* bufA = ws + (size_t)5 * N;
    float* bufB = ws + (size_t)69 * N;
    float* dinv = ws + (size_t)133 * N;

    // zero all accumulation buffers in one shot (dinv fully overwritten, no zero needed)
    hipMemsetAsync(ws, 0, (size_t)133 * N * sizeof(float), stream);

    deg_kernel <<<(E + 255) / 256, 256, 0, stream>>>(ei, E, deg);
    dinv_kernel<<<(N + 255) / 256, 256, 0, stream>>>(deg, dinv, N);

    // input path (2 channels)
    prop2_kernel<<<(E + 255) / 256, 256, 0, stream>>>(ei, E, dinv, x,   txa, N);
    prop2_kernel<<<(E + 255) / 256, 256, 0, stream>>>(ei, E, dinv, txa, txb, N);
    input_conv_kernel<<<(N * HID + 255) / 256, 256, 0, stream>>>(x, txa, txb, W1, b1, out, N);

    // hidden path (64 channels)
    long long work = (long long)E * HID;
    int pblocks = (int)((work + 255) / 256);
    prop64_kernel<<<pblocks, 256, 0, stream>>>(ei, E, dinv, h,    bufA, N);
    prop64_kernel<<<pblocks, 256, 0, stream>>>(ei, E, dinv, bufA, bufB, N);

    // fused hidden_conv + gates
    gate_kernel<<<(N + NPB - 1) / NPB, NPB * 64, 0, stream>>>(
        out, h, bufA, bufB, W2, b2, Wz, bz, Wr, br, Wc, bc, N);
}

// Round 2
// 667.594 us; speedup vs baseline: 2.2687x; 2.2687x over previous
//
#include <hip/hip_runtime.h>
#include <hip/hip_bf16.h>
#include <math.h>

#define HID 64

// swizzled LDS index for a [64 nodes][64 ch] tile: conflict-free for both
// fixed-node (staging) and fixed-channel (compute) access patterns.
#define IDX(n, j) (((n) << 6) | (((j) + (n)) & 63))

// ---------------- histogram: out-degree (src, float) + in-degree (dst, int) ----
__global__ void hist_kernel(const int* __restrict__ ei, int E,
                            float* __restrict__ degS, int* __restrict__ cnt) {
    int e = blockIdx.x * blockDim.x + threadIdx.x;
    if (e < E) {
        atomicAdd(&degS[ei[e]], 1.0f);
        atomicAdd(&cnt[ei[E + e]], 1);
    }
}

__global__ void dinv_kernel(const float* __restrict__ degS, float* __restrict__ dinv, int N) {
    int n = blockIdx.x * blockDim.x + threadIdx.x;
    if (n < N) {
        float dg = degS[n];
        dinv[n] = dg > 0.0f ? rsqrtf(fmaxf(dg, 1.0f)) : 0.0f;
    }
}

// ---------------- 3-kernel exclusive scan of cnt -> row (+cur copy) ----------
__global__ void scanA_kernel(const int* __restrict__ cnt, int* __restrict__ bs, int N) {
    __shared__ int s[256];
    int t = threadIdx.x, n = blockIdx.x * 256 + t;
    s[t] = (n < N) ? cnt[n] : 0;
    __syncthreads();
    for (int off = 128; off > 0; off >>= 1) {
        if (t < off) s[t] += s[t + off];
        __syncthreads();
    }
    if (t == 0) bs[blockIdx.x] = s[0];
}

__global__ void scanB_kernel(int* __restrict__ bs, int nb) {
    __shared__ int s[1024];
    int t = threadIdx.x;
    int orig = (t < nb) ? bs[t] : 0;
    s[t] = orig;
    __syncthreads();
    for (int off = 1; off < 1024; off <<= 1) {
        int v = (t >= off) ? s[t - off] : 0;
        __syncthreads();
        s[t] += v;
        __syncthreads();
    }
    if (t < nb) bs[t] = s[t] - orig;   // exclusive
}

__global__ void scanC_kernel(const int* __restrict__ cnt, const int* __restrict__ bs,
                             int* __restrict__ row, int* __restrict__ cur, int N) {
    __shared__ int s[256];
    int t = threadIdx.x, n = blockIdx.x * 256 + t;
    int c = (n < N) ? cnt[n] : 0;
    s[t] = c;
    __syncthreads();
    for (int off = 1; off < 256; off <<= 1) {
        int v = (t >= off) ? s[t - off] : 0;
        __syncthreads();
        s[t] += v;
        __syncthreads();
    }
    if (n < N) {
        int r = bs[blockIdx.x] + s[t] - c;
        row[n] = r;
        cur[n] = r;
    }
}

// ---------------- fill CSR: srcs sorted by dst ------------------------------
__global__ void fill_kernel(const int* __restrict__ ei, int E,
                            int* __restrict__ cur, int* __restrict__ srcs) {
    int e = blockIdx.x * blockDim.x + threadIdx.x;
    if (e < E) {
        int s = ei[e], d = ei[E + e];
        int p = atomicAdd(&cur[d], 1);
        srcs[p] = s;
    }
}

// ---------------- W2eff: rows 0..63 = W2[0]-W2[2]; 64..127 = W2[1]; 128..191 = 2*W2[2]
__global__ void w2eff_kernel(const float* __restrict__ W2, float* __restrict__ W2e) {
    int idx = blockIdx.x * blockDim.x + threadIdx.x;
    if (idx < 192 * 64) {
        int r = idx >> 6;
        float v;
        if (r < 64)       v = W2[idx] - W2[8192 + idx];
        else if (r < 128) v = W2[idx];
        else              v = 2.0f * W2[idx];
        W2e[idx] = v;
    }
}

// ---------------- 2-channel gather propagation (input path) -----------------
__global__ void gather2_kernel(const int* __restrict__ row, const int* __restrict__ cnt,
                               const int* __restrict__ srcs, const float* __restrict__ dinv,
                               const float* __restrict__ xsrc, float* __restrict__ dst, int N) {
    int n = blockIdx.x * blockDim.x + threadIdx.x;
    if (n >= N) return;
    int start = row[n], k = cnt[n];
    float dn = dinv[n];
    float a0 = 0.0f, a1 = 0.0f;
    const float2* x2 = (const float2*)xsrc;
    for (int q = 0; q < k; ++q) {
        int s = srcs[start + q];
        float w = dinv[s] * dn;
        float2 xv = x2[s];
        a0 = fmaf(w, xv.x, a0);
        a1 = fmaf(w, xv.y, a1);
    }
    dst[2 * n]     = -a0;
    dst[2 * n + 1] = -a1;
}

// ---------------- 64-channel gather propagation (hidden path) ---------------
// wave per node, lane = channel; no atomics; scalar loads for indices/weights.
__global__ void gather64_kernel(const int* __restrict__ row, const int* __restrict__ cnt,
                                const int* __restrict__ srcs, const float* __restrict__ dinv,
                                const float* __restrict__ src, float* __restrict__ dst, int N) {
    int wu = __builtin_amdgcn_readfirstlane((int)threadIdx.x >> 6);
    int n = blockIdx.x * 4 + wu;
    if (n >= N) return;
    int c = threadIdx.x & 63;
    int start = row[n], k = cnt[n];
    float dn = dinv[n];
    float acc = 0.0f;
    #pragma unroll 4
    for (int q = 0; q < k; ++q) {
        int s = srcs[start + q];
        float w = dinv[s] * dn;
        acc = fmaf(w, src[s * HID + c], acc);
    }
    dst[n * HID + c] = -acc;
}

// ---------------- fused input_conv + hidden_conv + GRU gates ----------------
// Block = 64 nodes, 256 threads (4 waves). Wave w computes channels [16w,16w+16)
// for all 64 nodes (lane = node). All weight loads are wave-uniform -> SGPR.
// outpp holds prop(prop(h)) on entry (read in staging), final output on exit.
__global__ void gate_fused_kernel(float* outpp,
                                  const float* __restrict__ x,
                                  const float* __restrict__ h,
                                  const float* __restrict__ txa,
                                  const float* __restrict__ txb,
                                  const float* __restrict__ bufA,
                                  const float* __restrict__ W1, const float* __restrict__ b1,
                                  const float* __restrict__ W2e, const float* __restrict__ b2,
                                  const float* __restrict__ Wz, const float* __restrict__ bz,
                                  const float* __restrict__ Wr, const float* __restrict__ br,
                                  const float* __restrict__ Wc, const float* __restrict__ bc,
                                  int N) {
    __shared__ float s_h [64 * 64];
    __shared__ float s_t1[64 * 64];   // prop(h); reused for r*hc in phase 3
    __shared__ float s_pp[64 * 64];
    __shared__ float s_ic[64 * 64];
    __shared__ float s_hc[64 * 64];

    int tid = threadIdx.x;
    int l   = tid & 63;                                        // lane: node in phases
    int wu  = __builtin_amdgcn_readfirstlane(tid >> 6);        // wave id (uniform)
    int wbase = wu * 16;
    int b0 = blockIdx.x * 64;

    // ---- staging: wave w stages node rep*4+w each rep; lane = channel ----
    float b1j = b1[l];
    float w10 = W1[l],       w11 = W1[64 + l],  w12 = W1[128 + l];
    float w13 = W1[192 + l], w14 = W1[256 + l], w15 = W1[320 + l];
    for (int rep = 0; rep < 16; ++rep) {
        int n = rep * 4 + wu;
        int g = b0 + n;
        int gc = g < N ? g : N - 1;
        float hv  = h[gc * 64 + l];
        float t1v = bufA[gc * 64 + l];
        float ppv = outpp[gc * 64 + l];
        float x0 = x[2 * gc], x1 = x[2 * gc + 1];
        float ta0 = txa[2 * gc], ta1 = txa[2 * gc + 1];
        float tb0 = txb[2 * gc], tb1 = txb[2 * gc + 1];
        float t20 = 2.0f * tb0 - x0, t21 = 2.0f * tb1 - x1;
        float icv = b1j + x0 * w10 + x1 * w11 + ta0 * w12 + ta1 * w13
                        + t20 * w14 + t21 * w15;
        s_h [IDX(n, l)] = hv;
        s_t1[IDX(n, l)] = t1v;
        s_pp[IDX(n, l)] = ppv;
        s_ic[IDX(n, l)] = icv;
    }
    __syncthreads();

    // ---- phase 1: hidden conv, K=192 over [h; t1; pp] with W2eff ----
    float acc[16];
    #pragma unroll
    for (int j2 = 0; j2 < 16; ++j2) acc[j2] = b2[wbase + j2];
    #pragma unroll 4
    for (int i = 0; i < 64; ++i) {
        float v = s_h[IDX(l, i)];
        #pragma unroll
        for (int j2 = 0; j2 < 16; ++j2)
            acc[j2] = fmaf(v, W2e[i * 64 + wbase + j2], acc[j2]);
    }
    #pragma unroll 4
    for (int i = 0; i < 64; ++i) {
        float v = s_t1[IDX(l, i)];
        #pragma unroll
        for (int j2 = 0; j2 < 16; ++j2)
            acc[j2] = fmaf(v, W2e[(64 + i) * 64 + wbase + j2], acc[j2]);
    }
    #pragma unroll 4
    for (int i = 0; i < 64; ++i) {
        float v = s_pp[IDX(l, i)];
        #pragma unroll
        for (int j2 = 0; j2 < 16; ++j2)
            acc[j2] = fmaf(v, W2e[(128 + i) * 64 + wbase + j2], acc[j2]);
    }
    #pragma unroll
    for (int j2 = 0; j2 < 16; ++j2) s_hc[IDX(l, wbase + j2)] = acc[j2];
    __syncthreads();

    // ---- phase 2: z and r gates over [ic; hc] ----
    float az[16], ar[16];
    #pragma unroll
    for (int j2 = 0; j2 < 16; ++j2) { az[j2] = bz[wbase + j2]; ar[j2] = br[wbase + j2]; }
    #pragma unroll 4
    for (int i = 0; i < 64; ++i) {
        float v = s_ic[IDX(l, i)];
        #pragma unroll
        for (int j2 = 0; j2 < 16; ++j2) {
            az[j2] = fmaf(v, Wz[i * 64 + wbase + j2], az[j2]);
            ar[j2] = fmaf(v, Wr[i * 64 + wbase + j2], ar[j2]);
        }
    }
    #pragma unroll 4
    for (int i = 0; i < 64; ++i) {
        float v = s_hc[IDX(l, i)];
        #pragma unroll
        for (int j2 = 0; j2 < 16; ++j2) {
            az[j2] = fmaf(v, Wz[(64 + i) * 64 + wbase + j2], az[j2]);
            ar[j2] = fmaf(v, Wr[(64 + i) * 64 + wbase + j2], ar[j2]);
        }
    }
    float zz[16];
    #pragma unroll
    for (int j2 = 0; j2 < 16; ++j2) {
        zz[j2] = 1.0f / (1.0f + expf(-az[j2]));
        float rr = 1.0f / (1.0f + expf(-ar[j2]));
        float hcv = s_hc[IDX(l, wbase + j2)];
        s_t1[IDX(l, wbase + j2)] = rr * hcv;          // r*hc (t1 is dead)
    }
    __syncthreads();

    // ---- phase 3: candidate over [ic; r*hc] ----
    float ac[16];
    #pragma unroll
    for (int j2 = 0; j2 < 16; ++j2) ac[j2] = bc[wbase + j2];
    #pragma unroll 4
    for (int i = 0; i < 64; ++i) {
        float v = s_ic[IDX(l, i)];
        #pragma unroll
        for (int j2 = 0; j2 < 16; ++j2)
            ac[j2] = fmaf(v, Wc[i * 64 + wbase + j2], ac[j2]);
    }
    #pragma unroll 4
    for (int i = 0; i < 64; ++i) {
        float v = s_t1[IDX(l, i)];
        #pragma unroll
        for (int j2 = 0; j2 < 16; ++j2)
            ac[j2] = fmaf(v, Wc[(64 + i) * 64 + wbase + j2], ac[j2]);
    }

    int gl = b0 + l;
    if (gl < N) {
        #pragma unroll
        for (int j2 = 0; j2 < 16; ++j2) {
            float ht = tanhf(ac[j2]);
            float hv = s_h[IDX(l, wbase + j2)];
            outpp[gl * 64 + wbase + j2] = zz[j2] * hv + (1.0f - zz[j2]) * ht;
        }
    }
}

extern "C" void kernel_launch(void* const* d_in, const int* in_sizes, int n_in,
                              void* d_out, int out_size, void* d_ws, size_t ws_size,
                              hipStream_t stream) {
    const float* x  = (const float*)d_in[0];
    const int*   ei = (const int*)  d_in[1];
    const float* h  = (const float*)d_in[2];
    const float* W1 = (const float*)d_in[3];
    const float* b1 = (const float*)d_in[4];
    const float* W2 = (const float*)d_in[5];
    const float* b2 = (const float*)d_in[6];
    const float* Wz = (const float*)d_in[7];
    const float* bz = (const float*)d_in[8];
    const float* Wr = (const float*)d_in[9];
    const float* br = (const float*)d_in[10];
    const float* Wc = (const float*)d_in[11];
    const float* bc = (const float*)d_in[12];
    float* out = (float*)d_out;

    int N = in_sizes[0] / 2;     // 100000
    int E = in_sizes[1] / 2;     // 1600000
    int NB = (N + 255) / 256;    // scan blocks (391)

    // workspace layout (4B units):
    char* wsb = (char*)d_ws;
    float* degS = (float*)wsb;                              // N  (memset w/ cnt)
    int*   cnt  = (int*)  (wsb + (size_t)N * 4);            // N  (memset)
    float* dinv = (float*)(wsb + (size_t)2 * N * 4);        // N
    int*   row  = (int*)  (wsb + (size_t)3 * N * 4);        // N
    int*   cur  = (int*)  (wsb + (size_t)4 * N * 4);        // N
    float* txa  = (float*)(wsb + (size_t)5 * N * 4);        // 2N
    float* txb  = (float*)(wsb + (size_t)7 * N * 4);        // 2N
    int*   bs   = (int*)  (wsb + (size_t)9 * N * 4);        // 1024
    float* W2e  = (float*)(wsb + ((size_t)9 * N + 1024) * 4);       // 12288
    int*   srcs = (int*)  (wsb + ((size_t)9 * N + 13312) * 4);      // E
    float* bufA = (float*)(wsb + ((size_t)9 * N + 13312 + E) * 4);  // 64N

    // zero only the histogram accumulators
    hipMemsetAsync(wsb, 0, (size_t)2 * N * 4, stream);

    hist_kernel <<<(E + 255) / 256, 256, 0, stream>>>(ei, E, degS, cnt);
    dinv_kernel <<<NB, 256, 0, stream>>>(degS, dinv, N);

    // CSR build
    scanA_kernel<<<NB, 256, 0, stream>>>(cnt, bs, N);
    scanB_kernel<<<1, 1024, 0, stream>>>(bs, NB);
    scanC_kernel<<<NB, 256, 0, stream>>>(cnt, bs, row, cur, N);
    fill_kernel <<<(E + 255) / 256, 256, 0, stream>>>(ei, E, cur, srcs);

    w2eff_kernel<<<(192 * 64 + 255) / 256, 256, 0, stream>>>(W2, W2e);

    // input path: x -> txa -> txb (2 channels, gather)
    gather2_kernel<<<NB, 256, 0, stream>>>(row, cnt, srcs, dinv, x,   txa, N);
    gather2_kernel<<<NB, 256, 0, stream>>>(row, cnt, srcs, dinv, txa, txb, N);

    // hidden path: h -> bufA -> d_out (64 channels, gather)
    int gblocks = (N + 3) / 4;
    gather64_kernel<<<gblocks, 256, 0, stream>>>(row, cnt, srcs, dinv, h,    bufA, N);
    gather64_kernel<<<gblocks, 256, 0, stream>>>(row, cnt, srcs, dinv, bufA, out,  N);

    // fused input_conv + hidden_conv + gates
    gate_fused_kernel<<<(N + 63) / 64, 256, 0, stream>>>(
        out, x, h, txa, txb, bufA, W1, b1, W2e, b2, Wz, bz, Wr, br, Wc, bc, N);
}

// Round 4
// 563.654 us; speedup vs baseline: 2.6870x; 1.1844x over previous
//
#include <hip/hip_runtime.h>
#include <hip/hip_bf16.h>
#include <math.h>

#define HID 64

// ---- bf16 pack/unpack (RNE) ----
__device__ __forceinline__ unsigned int bf16r(float f) {
    unsigned int u = __float_as_uint(f);
    return (u + 0x7fffu + ((u >> 16) & 1u)) >> 16;
}
__device__ __forceinline__ unsigned int pack2(float a, float b) {
    return bf16r(a) | (bf16r(b) << 16);
}
__device__ __forceinline__ float lo2f(unsigned int u) { return __uint_as_float(u << 16); }
__device__ __forceinline__ float hi2f(unsigned int u) { return __uint_as_float(u & 0xffff0000u); }

// ---------------- histogram: out-degree (src, float) + in-degree (dst, int) ----
__global__ void hist_kernel(const int* __restrict__ ei, int E,
                            float* __restrict__ degS, int* __restrict__ cnt) {
    int e = blockIdx.x * blockDim.x + threadIdx.x;
    if (e < E) {
        atomicAdd(&degS[ei[e]], 1.0f);
        atomicAdd(&cnt[ei[E + e]], 1);
    }
}

__global__ void dinv_kernel(const float* __restrict__ degS, float* __restrict__ dinv, int N) {
    int n = blockIdx.x * blockDim.x + threadIdx.x;
    if (n < N) {
        float dg = degS[n];
        dinv[n] = dg > 0.0f ? rsqrtf(fmaxf(dg, 1.0f)) : 0.0f;
    }
}

// ---------------- 3-kernel exclusive scan of cnt -> row (+cur copy) ----------
__global__ void scanA_kernel(const int* __restrict__ cnt, int* __restrict__ bs, int N) {
    __shared__ int s[256];
    int t = threadIdx.x, n = blockIdx.x * 256 + t;
    s[t] = (n < N) ? cnt[n] : 0;
    __syncthreads();
    for (int off = 128; off > 0; off >>= 1) {
        if (t < off) s[t] += s[t + off];
        __syncthreads();
    }
    if (t == 0) bs[blockIdx.x] = s[0];
}

__global__ void scanB_kernel(int* __restrict__ bs, int nb) {
    __shared__ int s[1024];
    int t = threadIdx.x;
    int orig = (t < nb) ? bs[t] : 0;
    s[t] = orig;
    __syncthreads();
    for (int off = 1; off < 1024; off <<= 1) {
        int v = (t >= off) ? s[t - off] : 0;
        __syncthreads();
        s[t] += v;
        __syncthreads();
    }
    if (t < nb) bs[t] = s[t] - orig;   // exclusive
}

__global__ void scanC_kernel(const int* __restrict__ cnt, const int* __restrict__ bs,
                             int* __restrict__ row, int* __restrict__ cur, int N) {
    __shared__ int s[256];
    int t = threadIdx.x, n = blockIdx.x * 256 + t;
    int c = (n < N) ? cnt[n] : 0;
    s[t] = c;
    __syncthreads();
    for (int off = 1; off < 256; off <<= 1) {
        int v = (t >= off) ? s[t - off] : 0;
        __syncthreads();
        s[t] += v;
        __syncthreads();
    }
    if (n < N) {
        int r = bs[blockIdx.x] + s[t] - c;
        row[n] = r;
        cur[n] = r;
    }
}

// ---------------- fill CSR: (src, dinv[src]) sorted by dst ------------------
__global__ void fill_kernel(const int* __restrict__ ei, int E,
                            const float* __restrict__ dinv,
                            int* __restrict__ cur, int2* __restrict__ srcw) {
    int e = blockIdx.x * blockDim.x + threadIdx.x;
    if (e < E) {
        int s = ei[e], d = ei[E + e];
        int p = atomicAdd(&cur[d], 1);
        srcw[p] = make_int2(s, __float_as_int(dinv[s]));
    }
}

// ---------------- W2eff: rows 0..63 = W2[0]-W2[2]; 64..127 = W2[1]; 128..191 = 2*W2[2]
__global__ void w2eff_kernel(const float* __restrict__ W2, float* __restrict__ W2e) {
    int idx = blockIdx.x * blockDim.x + threadIdx.x;
    if (idx < 192 * 64) {
        int r = idx >> 6;
        float v;
        if (r < 64)       v = W2[idx] - W2[8192 + idx];
        else if (r < 128) v = W2[idx];
        else              v = 2.0f * W2[idx];
        W2e[idx] = v;
    }
}

// ---------------- 2-channel gather propagation (input path) -----------------
__global__ void gather2_kernel(const int* __restrict__ row, const int* __restrict__ cnt,
                               const int2* __restrict__ srcw, const float* __restrict__ dinv,
                               const float* __restrict__ xsrc, float* __restrict__ dst, int N) {
    int n = blockIdx.x * blockDim.x + threadIdx.x;
    if (n >= N) return;
    int start = row[n], k = cnt[n];
    float a0 = 0.0f, a1 = 0.0f;
    const float2* x2 = (const float2*)xsrc;
    for (int q = 0; q < k; ++q) {
        int2 rec = srcw[start + q];
        float w = __int_as_float(rec.y);
        float2 xv = x2[rec.x];
        a0 = fmaf(w, xv.x, a0);
        a1 = fmaf(w, xv.y, a1);
    }
    float dn = dinv[n];
    dst[2 * n]     = -dn * a0;
    dst[2 * n + 1] = -dn * a1;
}

// ---------------- 64-channel gather propagation (hidden path) ---------------
// wave per node; 4 edges in flight (16 lanes x float4 each); no atomics.
__global__ void gather64_kernel(const int* __restrict__ row, const int* __restrict__ cnt,
                                const int2* __restrict__ srcw, const float* __restrict__ dinv,
                                const float* __restrict__ src, float* __restrict__ dst, int N) {
    int wu = __builtin_amdgcn_readfirstlane((int)threadIdx.x >> 6);
    int n = blockIdx.x * 4 + wu;
    if (n >= N) return;
    int lane = threadIdx.x & 63;
    int t = lane & 15;        // channel quad: channels 4t..4t+3
    int q = lane >> 4;        // edge slot 0..3
    int start = row[n], k = cnt[n];
    float ax = 0.0f, ay = 0.0f, az = 0.0f, aw = 0.0f;
    for (int e = q; e < k; e += 4) {
        int2 rec = srcw[start + e];
        float w = __int_as_float(rec.y);
        const float4* r4 = (const float4*)(src + (size_t)rec.x * HID);
        float4 v = r4[t];
        ax = fmaf(w, v.x, ax);
        ay = fmaf(w, v.y, ay);
        az = fmaf(w, v.z, az);
        aw = fmaf(w, v.w, aw);
    }
    // reduce across the 4 edge-slot groups (lanes differing in bits 4,5)
    ax += __shfl_xor(ax, 16); ay += __shfl_xor(ay, 16);
    az += __shfl_xor(az, 16); aw += __shfl_xor(aw, 16);
    ax += __shfl_xor(ax, 32); ay += __shfl_xor(ay, 32);
    az += __shfl_xor(az, 32); aw += __shfl_xor(aw, 32);
    if (q == 0) {
        float dn = -dinv[n];
        float4 o = make_float4(dn * ax, dn * ay, dn * az, dn * aw);
        ((float4*)(dst + (size_t)n * HID))[t] = o;
    }
}

// ---------------- fused input_conv + hidden_conv + GRU gates ----------------
// Block = 64 nodes, 256 threads (4 waves). Features staged in LDS as packed
// bf16 pairs (pair-rotation swizzle, <=2-way banks). Weights fp32 via SGPRs.
// Wave w computes channels [16w,16w+16) for all 64 nodes (lane = node).
__global__ __launch_bounds__(256, 4) void gate_fused_kernel(
    float* outpp,                       // in: prop(prop(h)); out: result
    const float* __restrict__ x,
    const float* __restrict__ h,
    const float* __restrict__ txa,
    const float* __restrict__ txb,
    const float* __restrict__ bufA,
    const float* __restrict__ W1, const float* __restrict__ b1,
    const float* __restrict__ W2e, const float* __restrict__ b2,
    const float* __restrict__ Wz, const float* __restrict__ bz,
    const float* __restrict__ Wr, const float* __restrict__ br,
    const float* __restrict__ Wc, const float* __restrict__ bc,
    int N) {
    __shared__ unsigned int s_h [2048];   // [64 nodes][32 ch-pairs] bf16x2
    __shared__ unsigned int s_t1[2048];   // prop(h); reused for r*hc
    __shared__ unsigned int s_pp[2048];
    __shared__ unsigned int s_ic[2048];
    __shared__ unsigned int s_hc[2048];

    int tid = threadIdx.x;
    int l   = tid & 63;                                 // node in compute phases
    int wu  = __builtin_amdgcn_readfirstlane(tid >> 6); // wave id
    int wbase = wu * 16;
    int b0 = blockIdx.x * 64;

    // ---- staging: lane = (node-pair selector, channel pair) ----
    int pc  = tid & 31;          // channel pair 0..31 (channels 2pc, 2pc+1)
    int sub = (tid >> 5) & 1;    // which of the wave's 2 nodes per rep

    const float2* h2  = (const float2*)h;
    const float2* a2  = (const float2*)bufA;
    const float2* o2  = (const float2*)outpp;
    const float2* x2  = (const float2*)x;
    const float2* ta2 = (const float2*)txa;
    const float2* tb2 = (const float2*)txb;

    float2 b1v  = ((const float2*)b1)[pc];
    float2 w1r0 = ((const float2*)(W1      ))[pc];
    float2 w1r1 = ((const float2*)(W1 +  64))[pc];
    float2 w1r2 = ((const float2*)(W1 + 128))[pc];
    float2 w1r3 = ((const float2*)(W1 + 192))[pc];
    float2 w1r4 = ((const float2*)(W1 + 256))[pc];
    float2 w1r5 = ((const float2*)(W1 + 320))[pc];

    #pragma unroll
    for (int rep = 0; rep < 8; ++rep) {
        int n = rep * 8 + wu * 2 + sub;
        int g = b0 + n;
        int gc = g < N ? g : N - 1;
        float2 hv  = h2[(size_t)gc * 32 + pc];
        float2 t1v = a2[(size_t)gc * 32 + pc];
        float2 ppv = o2[(size_t)gc * 32 + pc];
        float2 xv  = x2[gc];
        float2 tav = ta2[gc];
        float2 tbv = tb2[gc];
        float t20 = 2.0f * tbv.x - xv.x, t21 = 2.0f * tbv.y - xv.y;
        float ic0 = b1v.x + xv.x * w1r0.x + xv.y * w1r1.x + tav.x * w1r2.x
                  + tav.y * w1r3.x + t20 * w1r4.x + t21 * w1r5.x;
        float ic1 = b1v.y + xv.x * w1r0.y + xv.y * w1r1.y + tav.x * w1r2.y
                  + tav.y * w1r3.y + t20 * w1r4.y + t21 * w1r5.y;
        int si = (n << 5) | ((pc + n) & 31);
        s_h [si] = pack2(hv.x,  hv.y);
        s_t1[si] = pack2(t1v.x, t1v.y);
        s_pp[si] = pack2(ppv.x, ppv.y);
        s_ic[si] = pack2(ic0,   ic1);
    }
    __syncthreads();

    int rbase = l << 5;

    // ---- phase 1: hidden conv, K=192 over [h; t1; pp] with W2eff ----
    float acc[16];
    #pragma unroll
    for (int j = 0; j < 16; ++j) acc[j] = b2[wbase + j];
    #pragma unroll 4
    for (int p = 0; p < 32; ++p) {
        unsigned int u = s_h[rbase | ((p + l) & 31)];
        float f0 = lo2f(u), f1 = hi2f(u);
        const float* wr0 = W2e + (2 * p) * 64 + wbase;
        #pragma unroll
        for (int j = 0; j < 16; ++j)
            acc[j] = fmaf(f0, wr0[j], fmaf(f1, wr0[64 + j], acc[j]));
    }
    #pragma unroll 4
    for (int p = 0; p < 32; ++p) {
        unsigned int u = s_t1[rbase | ((p + l) & 31)];
        float f0 = lo2f(u), f1 = hi2f(u);
        const float* wr0 = W2e + (64 + 2 * p) * 64 + wbase;
        #pragma unroll
        for (int j = 0; j < 16; ++j)
            acc[j] = fmaf(f0, wr0[j], fmaf(f1, wr0[64 + j], acc[j]));
    }
    #pragma unroll 4
    for (int p = 0; p < 32; ++p) {
        unsigned int u = s_pp[rbase | ((p + l) & 31)];
        float f0 = lo2f(u), f1 = hi2f(u);
        const float* wr0 = W2e + (128 + 2 * p) * 64 + wbase;
        #pragma unroll
        for (int j = 0; j < 16; ++j)
            acc[j] = fmaf(f0, wr0[j], fmaf(f1, wr0[64 + j], acc[j]));
    }
    #pragma unroll
    for (int j = 0; j < 8; ++j)
        s_hc[rbase | (((wbase >> 1) + j + l) & 31)] = pack2(acc[2 * j], acc[2 * j + 1]);
    __syncthreads();

    // ---- phase 2: z and r gates over [ic; hc] ----
    // combined = [ic, hc]; hc-half uses weight rows 64+channel -> (64 + 2p)*64.
    float az[16], ar[16];
    #pragma unroll
    for (int j = 0; j < 16; ++j) { az[j] = bz[wbase + j]; ar[j] = br[wbase + j]; }
    #pragma unroll 2
    for (int p = 0; p < 32; ++p) {
        unsigned int u = s_ic[rbase | ((p + l) & 31)];
        float f0 = lo2f(u), f1 = hi2f(u);
        const float* wz0 = Wz + (2 * p) * 64 + wbase;
        const float* wr0 = Wr + (2 * p) * 64 + wbase;
        #pragma unroll
        for (int j = 0; j < 16; ++j) {
            az[j] = fmaf(f0, wz0[j], fmaf(f1, wz0[64 + j], az[j]));
            ar[j] = fmaf(f0, wr0[j], fmaf(f1, wr0[64 + j], ar[j]));
        }
    }
    #pragma unroll 2
    for (int p = 0; p < 32; ++p) {
        unsigned int u = s_hc[rbase | ((p + l) & 31)];
        float f0 = lo2f(u), f1 = hi2f(u);
        const float* wz0 = Wz + (64 + 2 * p) * 64 + wbase;
        const float* wr0 = Wr + (64 + 2 * p) * 64 + wbase;
        #pragma unroll
        for (int j = 0; j < 16; ++j) {
            az[j] = fmaf(f0, wz0[j], fmaf(f1, wz0[64 + j], az[j]));
            ar[j] = fmaf(f0, wr0[j], fmaf(f1, wr0[64 + j], ar[j]));
        }
    }
    float zz[16];
    float rr[16];
    #pragma unroll
    for (int j = 0; j < 16; ++j) {
        zz[j] = 1.0f / (1.0f + __expf(-az[j]));
        rr[j] = 1.0f / (1.0f + __expf(-ar[j]));
    }
    #pragma unroll
    for (int j = 0; j < 8; ++j)
        s_t1[rbase | (((wbase >> 1) + j + l) & 31)] =
            pack2(rr[2 * j] * acc[2 * j], rr[2 * j + 1] * acc[2 * j + 1]);
    __syncthreads();

    // ---- phase 3: candidate over [ic; r*hc] ----
    float ac[16];
    #pragma unroll
    for (int j = 0; j < 16; ++j) ac[j] = bc[wbase + j];
    #pragma unroll 4
    for (int p = 0; p < 32; ++p) {
        unsigned int u = s_ic[rbase | ((p + l) & 31)];
        float f0 = lo2f(u), f1 = hi2f(u);
        const float* wc0 = Wc + (2 * p) * 64 + wbase;
        #pragma unroll
        for (int j = 0; j < 16; ++j)
            ac[j] = fmaf(f0, wc0[j], fmaf(f1, wc0[64 + j], ac[j]));
    }
    #pragma unroll 4
    for (int p = 0; p < 32; ++p) {
        unsigned int u = s_t1[rbase | ((p + l) & 31)];
        float f0 = lo2f(u), f1 = hi2f(u);
        const float* wc0 = Wc + (64 + 2 * p) * 64 + wbase;
        #pragma unroll
        for (int j = 0; j < 16; ++j)
            ac[j] = fmaf(f0, wc0[j], fmaf(f1, wc0[64 + j], ac[j]));
    }

    int gl = b0 + l;
    if (gl < N) {
        const float2* hrow = (const float2*)(h + (size_t)gl * 64 + wbase);
        float2* orow = (float2*)(outpp + (size_t)gl * 64 + wbase);
        #pragma unroll
        for (int j = 0; j < 8; ++j) {
            float2 hv = hrow[j];
            float a0 = fminf(fmaxf(ac[2 * j],     -40.0f), 40.0f);
            float a1 = fminf(fmaxf(ac[2 * j + 1], -40.0f), 40.0f);
            float e0 = __expf(2.0f * a0);
            float e1 = __expf(2.0f * a1);
            float ht0 = 1.0f - 2.0f / (e0 + 1.0f);
            float ht1 = 1.0f - 2.0f / (e1 + 1.0f);
            float o0 = zz[2 * j]     * hv.x + (1.0f - zz[2 * j])     * ht0;
            float o1 = zz[2 * j + 1] * hv.y + (1.0f - zz[2 * j + 1]) * ht1;
            orow[j] = make_float2(o0, o1);
        }
    }
}

extern "C" void kernel_launch(void* const* d_in, const int* in_sizes, int n_in,
                              void* d_out, int out_size, void* d_ws, size_t ws_size,
                              hipStream_t stream) {
    const float* x  = (const float*)d_in[0];
    const int*   ei = (const int*)  d_in[1];
    const float* h  = (const float*)d_in[2];
    const float* W1 = (const float*)d_in[3];
    const float* b1 = (const float*)d_in[4];
    const float* W2 = (const float*)d_in[5];
    const float* b2 = (const float*)d_in[6];
    const float* Wz = (const float*)d_in[7];
    const float* bz = (const float*)d_in[8];
    const float* Wr = (const float*)d_in[9];
    const float* br = (const float*)d_in[10];
    const float* Wc = (const float*)d_in[11];
    const float* bc = (const float*)d_in[12];
    float* out = (float*)d_out;

    int N = in_sizes[0] / 2;     // 100000
    int E = in_sizes[1] / 2;     // 1600000
    int NB = (N + 255) / 256;    // scan blocks (391)

    // workspace layout (4B units):
    char* wsb = (char*)d_ws;
    float* degS = (float*)wsb;                              // N  (memset)
    int*   cnt  = (int*)  (wsb + (size_t)N * 4);            // N  (memset)
    float* dinv = (float*)(wsb + (size_t)2 * N * 4);        // N
    int*   row  = (int*)  (wsb + (size_t)3 * N * 4);        // N
    int*   cur  = (int*)  (wsb + (size_t)4 * N * 4);        // N
    float* txa  = (float*)(wsb + (size_t)5 * N * 4);        // 2N
    float* txb  = (float*)(wsb + (size_t)7 * N * 4);        // 2N
    int*   bs   = (int*)  (wsb + (size_t)9 * N * 4);        // 1024
    float* W2e  = (float*)(wsb + ((size_t)9 * N + 1024) * 4);          // 12288
    int2*  srcw = (int2*) (wsb + ((size_t)9 * N + 13312) * 4);         // 2E (8B recs)
    float* bufA = (float*)(wsb + ((size_t)9 * N + 13312 + 2 * (size_t)E) * 4); // 64N

    // zero only the histogram accumulators
    hipMemsetAsync(wsb, 0, (size_t)2 * N * 4, stream);

    hist_kernel <<<(E + 255) / 256, 256, 0, stream>>>(ei, E, degS, cnt);
    dinv_kernel <<<NB, 256, 0, stream>>>(degS, dinv, N);

    // CSR build (srcs sorted by dst, weight = dinv[src] fused in)
    scanA_kernel<<<NB, 256, 0, stream>>>(cnt, bs, N);
    scanB_kernel<<<1, 1024, 0, stream>>>(bs, NB);
    scanC_kernel<<<NB, 256, 0, stream>>>(cnt, bs, row, cur, N);
    fill_kernel <<<(E + 255) / 256, 256, 0, stream>>>(ei, E, dinv, cur, srcw);

    w2eff_kernel<<<(192 * 64 + 255) / 256, 256, 0, stream>>>(W2, W2e);

    // input path: x -> txa -> txb (2 channels, gather)
    gather2_kernel<<<NB, 256, 0, stream>>>(row, cnt, srcw, dinv, x,   txa, N);
    gather2_kernel<<<NB, 256, 0, stream>>>(row, cnt, srcw, dinv, txa, txb, N);

    // hidden path: h -> bufA -> d_out (64 channels, gather)
    int gblocks = (N + 3) / 4;
    gather64_kernel<<<gblocks, 256, 0, stream>>>(row, cnt, srcw, dinv, h,    bufA, N);
    gather64_kernel<<<gblocks, 256, 0, stream>>>(row, cnt, srcw, dinv, bufA, out,  N);

    // fused input_conv + hidden_conv + gates
    gate_fused_kernel<<<(N + 63) / 64, 256, 0, stream>>>(
        out, x, h, txa, txb, bufA, W1, b1, W2e, b2, Wz, bz, Wr, br, Wc, bc, N);
}

// Round 5
// 536.531 us; speedup vs baseline: 2.8229x; 1.0506x over previous
//
#include <hip/hip_runtime.h>
#include <hip/hip_bf16.h>
#include <math.h>

#define HID 64

// ---- bf16 pack/unpack (RNE) ----
__device__ __forceinline__ unsigned int bf16r(float f) {
    unsigned int u = __float_as_uint(f);
    return (u + 0x7fffu + ((u >> 16) & 1u)) >> 16;
}
__device__ __forceinline__ unsigned int pack2(float a, float b) {
    return bf16r(a) | (bf16r(b) << 16);
}
__device__ __forceinline__ float lo2f(unsigned int u) { return __uint_as_float(u << 16); }
__device__ __forceinline__ float hi2f(unsigned int u) { return __uint_as_float(u & 0xffff0000u); }

// ---------------- histogram: out-degree (src, float) + in-degree (dst, int) ----
__global__ void hist_kernel(const int* __restrict__ ei, int E,
                            float* __restrict__ degS, int* __restrict__ cnt) {
    int e = blockIdx.x * blockDim.x + threadIdx.x;
    if (e < E) {
        atomicAdd(&degS[ei[e]], 1.0f);
        atomicAdd(&cnt[ei[E + e]], 1);
    }
}

__global__ void dinv_kernel(const float* __restrict__ degS, float* __restrict__ dinv, int N) {
    int n = blockIdx.x * blockDim.x + threadIdx.x;
    if (n < N) {
        float dg = degS[n];
        dinv[n] = dg > 0.0f ? rsqrtf(fmaxf(dg, 1.0f)) : 0.0f;
    }
}

// ---------------- 3-kernel exclusive scan of cnt -> row (+cur copy) ----------
__global__ void scanA_kernel(const int* __restrict__ cnt, int* __restrict__ bs, int N) {
    __shared__ int s[256];
    int t = threadIdx.x, n = blockIdx.x * 256 + t;
    s[t] = (n < N) ? cnt[n] : 0;
    __syncthreads();
    for (int off = 128; off > 0; off >>= 1) {
        if (t < off) s[t] += s[t + off];
        __syncthreads();
    }
    if (t == 0) bs[blockIdx.x] = s[0];
}

__global__ void scanB_kernel(int* __restrict__ bs, int nb) {
    __shared__ int s[1024];
    int t = threadIdx.x;
    int orig = (t < nb) ? bs[t] : 0;
    s[t] = orig;
    __syncthreads();
    for (int off = 1; off < 1024; off <<= 1) {
        int v = (t >= off) ? s[t - off] : 0;
        __syncthreads();
        s[t] += v;
        __syncthreads();
    }
    if (t < nb) bs[t] = s[t] - orig;   // exclusive
}

__global__ void scanC_kernel(const int* __restrict__ cnt, const int* __restrict__ bs,
                             int* __restrict__ row, int* __restrict__ cur, int N) {
    __shared__ int s[256];
    int t = threadIdx.x, n = blockIdx.x * 256 + t;
    int c = (n < N) ? cnt[n] : 0;
    s[t] = c;
    __syncthreads();
    for (int off = 1; off < 256; off <<= 1) {
        int v = (t >= off) ? s[t - off] : 0;
        __syncthreads();
        s[t] += v;
        __syncthreads();
    }
    if (n < N) {
        int r = bs[blockIdx.x] + s[t] - c;
        row[n] = r;
        cur[n] = r;
    }
}

// ---------------- fill CSR: (src, dinv[src]) sorted by dst ------------------
__global__ void fill_kernel(const int* __restrict__ ei, int E,
                            const float* __restrict__ dinv,
                            int* __restrict__ cur, int2* __restrict__ srcw) {
    int e = blockIdx.x * blockDim.x + threadIdx.x;
    if (e < E) {
        int s = ei[e], d = ei[E + e];
        int p = atomicAdd(&cur[d], 1);
        srcw[p] = make_int2(s, __float_as_int(dinv[s]));
    }
}

// ---------------- W2eff: rows 0..63 = W2[0]-W2[2]; 64..127 = W2[1]; 128..191 = 2*W2[2]
__global__ void w2eff_kernel(const float* __restrict__ W2, float* __restrict__ W2e) {
    int idx = blockIdx.x * blockDim.x + threadIdx.x;
    if (idx < 192 * 64) {
        int r = idx >> 6;
        float v;
        if (r < 64)       v = W2[idx] - W2[8192 + idx];
        else if (r < 128) v = W2[idx];
        else              v = 2.0f * W2[idx];
        W2e[idx] = v;
    }
}

// ---------------- pack h (fp32) -> bf16x2 table ------------------------------
__global__ void packh_kernel(const float* __restrict__ h, unsigned int* __restrict__ hbf,
                             int total2) {
    int i = blockIdx.x * blockDim.x + threadIdx.x;
    if (i < total2) {
        float2 v = ((const float2*)h)[i];
        hbf[i] = pack2(v.x, v.y);
    }
}

// ---------------- 2-channel gather propagation (input path) -----------------
__global__ void gather2_kernel(const int* __restrict__ row, const int* __restrict__ cnt,
                               const int2* __restrict__ srcw, const float* __restrict__ dinv,
                               const float* __restrict__ xsrc, float* __restrict__ dst, int N) {
    int n = blockIdx.x * blockDim.x + threadIdx.x;
    if (n >= N) return;
    int start = row[n], k = cnt[n];
    float a0 = 0.0f, a1 = 0.0f;
    const float2* x2 = (const float2*)xsrc;
    for (int q = 0; q < k; ++q) {
        int2 rec = srcw[start + q];
        float w = __int_as_float(rec.y);
        float2 xv = x2[rec.x];
        a0 = fmaf(w, xv.x, a0);
        a1 = fmaf(w, xv.y, a1);
    }
    float dn = dinv[n];
    dst[2 * n]     = -dn * a0;
    dst[2 * n + 1] = -dn * a1;
}

// ---------------- 64-channel gather propagation, bf16 rows -------------------
// wave per node; 8 edges in flight (8 lanes x dwordx4 = 128B row each).
__global__ void gather64_kernel(const int* __restrict__ row, const int* __restrict__ cnt,
                                const int2* __restrict__ srcw, const float* __restrict__ dinv,
                                const unsigned int* __restrict__ src,  // bf16 rows, 32 u32/row
                                unsigned int* __restrict__ dst, int N) {
    int wu = __builtin_amdgcn_readfirstlane((int)threadIdx.x >> 6);
    int n = blockIdx.x * 4 + wu;
    if (n >= N) return;
    int lane = threadIdx.x & 63;
    int t    = lane & 7;      // u32 quad within row: u32s 4t..4t+3 (channels 8t..8t+7)
    int slot = lane >> 3;     // edge slot 0..7
    int start = row[n], k = cnt[n];
    float a0 = 0, a1 = 0, a2 = 0, a3 = 0, a4 = 0, a5 = 0, a6 = 0, a7 = 0;
    for (int e = slot; e < k; e += 8) {
        int2 rec = srcw[start + e];
        float w = __int_as_float(rec.y);
        const uint4* r4 = (const uint4*)(src + (size_t)rec.x * 32);
        uint4 v = r4[t];
        a0 = fmaf(w, lo2f(v.x), a0); a1 = fmaf(w, hi2f(v.x), a1);
        a2 = fmaf(w, lo2f(v.y), a2); a3 = fmaf(w, hi2f(v.y), a3);
        a4 = fmaf(w, lo2f(v.z), a4); a5 = fmaf(w, hi2f(v.z), a5);
        a6 = fmaf(w, lo2f(v.w), a6); a7 = fmaf(w, hi2f(v.w), a7);
    }
    // reduce across the 8 edge slots (lanes differing in bits 3,4,5)
    a0 += __shfl_xor(a0, 8);  a1 += __shfl_xor(a1, 8);
    a2 += __shfl_xor(a2, 8);  a3 += __shfl_xor(a3, 8);
    a4 += __shfl_xor(a4, 8);  a5 += __shfl_xor(a5, 8);
    a6 += __shfl_xor(a6, 8);  a7 += __shfl_xor(a7, 8);
    a0 += __shfl_xor(a0, 16); a1 += __shfl_xor(a1, 16);
    a2 += __shfl_xor(a2, 16); a3 += __shfl_xor(a3, 16);
    a4 += __shfl_xor(a4, 16); a5 += __shfl_xor(a5, 16);
    a6 += __shfl_xor(a6, 16); a7 += __shfl_xor(a7, 16);
    a0 += __shfl_xor(a0, 32); a1 += __shfl_xor(a1, 32);
    a2 += __shfl_xor(a2, 32); a3 += __shfl_xor(a3, 32);
    a4 += __shfl_xor(a4, 32); a5 += __shfl_xor(a5, 32);
    a6 += __shfl_xor(a6, 32); a7 += __shfl_xor(a7, 32);
    if (slot == 0) {
        float dn = -dinv[n];
        uint4 o;
        o.x = pack2(dn * a0, dn * a1);
        o.y = pack2(dn * a2, dn * a3);
        o.z = pack2(dn * a4, dn * a5);
        o.w = pack2(dn * a6, dn * a7);
        ((uint4*)(dst + (size_t)n * 32))[t] = o;
    }
}

// ---------------- fused input_conv + hidden_conv + GRU gates ----------------
// Persistent: 1024 blocks (4/CU) stride over node tiles of 64. Features staged
// in LDS as bf16 pairs (pair-rotation swizzle). Weights fp32 via SGPRs.
// Wave w computes channels [16w,16w+16) for all 64 nodes (lane = node).
__global__ __launch_bounds__(256, 4) void gate_fused_kernel(
    float* __restrict__ out,
    const float* __restrict__ x,
    const float* __restrict__ h,
    const float* __restrict__ txa,
    const float* __restrict__ txb,
    const unsigned int* __restrict__ t1u,   // bufA bf16 rows (prop(h))
    const unsigned int* __restrict__ ppu,   // ppbf bf16 rows (prop(prop(h)))
    const float* __restrict__ W1, const float* __restrict__ b1,
    const float* __restrict__ W2e, const float* __restrict__ b2,
    const float* __restrict__ Wz, const float* __restrict__ bz,
    const float* __restrict__ Wr, const float* __restrict__ br,
    const float* __restrict__ Wc, const float* __restrict__ bc,
    int N) {
    __shared__ unsigned int s_h [2048];   // [64 nodes][32 ch-pairs] bf16x2
    __shared__ unsigned int s_t1[2048];   // prop(h); reused for r*hc
    __shared__ unsigned int s_pp[2048];
    __shared__ unsigned int s_ic[2048];
    __shared__ unsigned int s_hc[2048];

    int tid = threadIdx.x;
    int l   = tid & 63;                                 // node in compute phases
    int wu  = __builtin_amdgcn_readfirstlane(tid >> 6); // wave id
    int wbase = wu * 16;

    int pc  = tid & 31;          // channel pair 0..31
    int sub = (tid >> 5) & 1;    // which of the wave's 2 nodes per rep

    const float2* h2  = (const float2*)h;
    const float2* x2  = (const float2*)x;
    const float2* ta2 = (const float2*)txa;
    const float2* tb2 = (const float2*)txb;

    float2 b1v  = ((const float2*)b1)[pc];
    float2 w1r0 = ((const float2*)(W1      ))[pc];
    float2 w1r1 = ((const float2*)(W1 +  64))[pc];
    float2 w1r2 = ((const float2*)(W1 + 128))[pc];
    float2 w1r3 = ((const float2*)(W1 + 192))[pc];
    float2 w1r4 = ((const float2*)(W1 + 256))[pc];
    float2 w1r5 = ((const float2*)(W1 + 320))[pc];

    int T = (N + 63) / 64;
    for (int tile = blockIdx.x; tile < T; tile += gridDim.x) {
        int b0 = tile * 64;

        // ---- staging ----
        #pragma unroll
        for (int rep = 0; rep < 8; ++rep) {
            int n = rep * 8 + wu * 2 + sub;
            int g = b0 + n;
            int gc = g < N ? g : N - 1;
            float2 hv  = h2[(size_t)gc * 32 + pc];
            unsigned int t1v = t1u[(size_t)gc * 32 + pc];
            unsigned int ppv = ppu[(size_t)gc * 32 + pc];
            float2 xv  = x2[gc];
            float2 tav = ta2[gc];
            float2 tbv = tb2[gc];
            float t20 = 2.0f * tbv.x - xv.x, t21 = 2.0f * tbv.y - xv.y;
            float ic0 = b1v.x + xv.x * w1r0.x + xv.y * w1r1.x + tav.x * w1r2.x
                      + tav.y * w1r3.x + t20 * w1r4.x + t21 * w1r5.x;
            float ic1 = b1v.y + xv.x * w1r0.y + xv.y * w1r1.y + tav.x * w1r2.y
                      + tav.y * w1r3.y + t20 * w1r4.y + t21 * w1r5.y;
            int si = (n << 5) | ((pc + n) & 31);
            s_h [si] = pack2(hv.x, hv.y);
            s_t1[si] = t1v;
            s_pp[si] = ppv;
            s_ic[si] = pack2(ic0, ic1);
        }
        __syncthreads();

        int rbase = l << 5;

        // ---- phase 1: hidden conv, K=192 over [h; t1; pp] with W2eff ----
        float acc[16];
        #pragma unroll
        for (int j = 0; j < 16; ++j) acc[j] = b2[wbase + j];
        #pragma unroll 4
        for (int p = 0; p < 32; ++p) {
            unsigned int u = s_h[rbase | ((p + l) & 31)];
            float f0 = lo2f(u), f1 = hi2f(u);
            const float* wr0 = W2e + (2 * p) * 64 + wbase;
            #pragma unroll
            for (int j = 0; j < 16; ++j)
                acc[j] = fmaf(f0, wr0[j], fmaf(f1, wr0[64 + j], acc[j]));
        }
        #pragma unroll 4
        for (int p = 0; p < 32; ++p) {
            unsigned int u = s_t1[rbase | ((p + l) & 31)];
            float f0 = lo2f(u), f1 = hi2f(u);
            const float* wr0 = W2e + (64 + 2 * p) * 64 + wbase;
            #pragma unroll
            for (int j = 0; j < 16; ++j)
                acc[j] = fmaf(f0, wr0[j], fmaf(f1, wr0[64 + j], acc[j]));
        }
        #pragma unroll 4
        for (int p = 0; p < 32; ++p) {
            unsigned int u = s_pp[rbase | ((p + l) & 31)];
            float f0 = lo2f(u), f1 = hi2f(u);
            const float* wr0 = W2e + (128 + 2 * p) * 64 + wbase;
            #pragma unroll
            for (int j = 0; j < 16; ++j)
                acc[j] = fmaf(f0, wr0[j], fmaf(f1, wr0[64 + j], acc[j]));
        }
        #pragma unroll
        for (int j = 0; j < 8; ++j)
            s_hc[rbase | (((wbase >> 1) + j + l) & 31)] = pack2(acc[2 * j], acc[2 * j + 1]);
        __syncthreads();

        // ---- phase 2: z and r gates over [ic; hc] (hc rows at 64+ch) ----
        float az[16], ar[16];
        #pragma unroll
        for (int j = 0; j < 16; ++j) { az[j] = bz[wbase + j]; ar[j] = br[wbase + j]; }
        #pragma unroll 2
        for (int p = 0; p < 32; ++p) {
            unsigned int u = s_ic[rbase | ((p + l) & 31)];
            float f0 = lo2f(u), f1 = hi2f(u);
            const float* wz0 = Wz + (2 * p) * 64 + wbase;
            const float* wr0 = Wr + (2 * p) * 64 + wbase;
            #pragma unroll
            for (int j = 0; j < 16; ++j) {
                az[j] = fmaf(f0, wz0[j], fmaf(f1, wz0[64 + j], az[j]));
                ar[j] = fmaf(f0, wr0[j], fmaf(f1, wr0[64 + j], ar[j]));
            }
        }
        #pragma unroll 2
        for (int p = 0; p < 32; ++p) {
            unsigned int u = s_hc[rbase | ((p + l) & 31)];
            float f0 = lo2f(u), f1 = hi2f(u);
            const float* wz0 = Wz + (64 + 2 * p) * 64 + wbase;
            const float* wr0 = Wr + (64 + 2 * p) * 64 + wbase;
            #pragma unroll
            for (int j = 0; j < 16; ++j) {
                az[j] = fmaf(f0, wz0[j], fmaf(f1, wz0[64 + j], az[j]));
                ar[j] = fmaf(f0, wr0[j], fmaf(f1, wr0[64 + j], ar[j]));
            }
        }
        float zz[16];
        float rr[16];
        #pragma unroll
        for (int j = 0; j < 16; ++j) {
            zz[j] = 1.0f / (1.0f + __expf(-az[j]));
            rr[j] = 1.0f / (1.0f + __expf(-ar[j]));
        }
        #pragma unroll
        for (int j = 0; j < 8; ++j)
            s_t1[rbase | (((wbase >> 1) + j + l) & 31)] =
                pack2(rr[2 * j] * acc[2 * j], rr[2 * j + 1] * acc[2 * j + 1]);
        __syncthreads();

        // ---- phase 3: candidate over [ic; r*hc] ----
        float ac[16];
        #pragma unroll
        for (int j = 0; j < 16; ++j) ac[j] = bc[wbase + j];
        #pragma unroll 4
        for (int p = 0; p < 32; ++p) {
            unsigned int u = s_ic[rbase | ((p + l) & 31)];
            float f0 = lo2f(u), f1 = hi2f(u);
            const float* wc0 = Wc + (2 * p) * 64 + wbase;
            #pragma unroll
            for (int j = 0; j < 16; ++j)
                ac[j] = fmaf(f0, wc0[j], fmaf(f1, wc0[64 + j], ac[j]));
        }
        #pragma unroll 4
        for (int p = 0; p < 32; ++p) {
            unsigned int u = s_t1[rbase | ((p + l) & 31)];
            float f0 = lo2f(u), f1 = hi2f(u);
            const float* wc0 = Wc + (64 + 2 * p) * 64 + wbase;
            #pragma unroll
            for (int j = 0; j < 16; ++j)
                ac[j] = fmaf(f0, wc0[j], fmaf(f1, wc0[64 + j], ac[j]));
        }

        int gl = b0 + l;
        if (gl < N) {
            const float2* hrow = (const float2*)(h + (size_t)gl * 64 + wbase);
            float2* orow = (float2*)(out + (size_t)gl * 64 + wbase);
            #pragma unroll
            for (int j = 0; j < 8; ++j) {
                float2 hv = hrow[j];
                float a0 = fminf(fmaxf(ac[2 * j],     -40.0f), 40.0f);
                float a1 = fminf(fmaxf(ac[2 * j + 1], -40.0f), 40.0f);
                float e0 = __expf(2.0f * a0);
                float e1 = __expf(2.0f * a1);
                float ht0 = 1.0f - 2.0f / (e0 + 1.0f);
                float ht1 = 1.0f - 2.0f / (e1 + 1.0f);
                float o0 = zz[2 * j]     * hv.x + (1.0f - zz[2 * j])     * ht0;
                float o1 = zz[2 * j + 1] * hv.y + (1.0f - zz[2 * j + 1]) * ht1;
                orow[j] = make_float2(o0, o1);
            }
        }
        __syncthreads();   // protect LDS before next tile's staging
    }
}

extern "C" void kernel_launch(void* const* d_in, const int* in_sizes, int n_in,
                              void* d_out, int out_size, void* d_ws, size_t ws_size,
                              hipStream_t stream) {
    const float* x  = (const float*)d_in[0];
    const int*   ei = (const int*)  d_in[1];
    const float* h  = (const float*)d_in[2];
    const float* W1 = (const float*)d_in[3];
    const float* b1 = (const float*)d_in[4];
    const float* W2 = (const float*)d_in[5];
    const float* b2 = (const float*)d_in[6];
    const float* Wz = (const float*)d_in[7];
    const float* bz = (const float*)d_in[8];
    const float* Wr = (const float*)d_in[9];
    const float* br = (const float*)d_in[10];
    const float* Wc = (const float*)d_in[11];
    const float* bc = (const float*)d_in[12];
    float* out = (float*)d_out;

    int N = in_sizes[0] / 2;     // 100000
    int E = in_sizes[1] / 2;     // 1600000
    int NB = (N + 255) / 256;    // scan blocks (391)

    // workspace layout (4B units):
    char* wsb = (char*)d_ws;
    float* degS = (float*)wsb;                              // N  (memset)
    int*   cnt  = (int*)  (wsb + (size_t)N * 4);            // N  (memset)
    float* dinv = (float*)(wsb + (size_t)2 * N * 4);        // N
    int*   row  = (int*)  (wsb + (size_t)3 * N * 4);        // N
    int*   cur  = (int*)  (wsb + (size_t)4 * N * 4);        // N
    float* txa  = (float*)(wsb + (size_t)5 * N * 4);        // 2N
    float* txb  = (float*)(wsb + (size_t)7 * N * 4);        // 2N
    int*   bs   = (int*)  (wsb + (size_t)9 * N * 4);        // 1024
    float* W2e  = (float*)(wsb + ((size_t)9 * N + 1024) * 4);          // 12288
    int2*  srcw = (int2*) (wsb + ((size_t)9 * N + 13312) * 4);         // 2E u32
    unsigned int* bufA = (unsigned int*)(wsb + ((size_t)9 * N + 13312 + 2 * (size_t)E) * 4);        // 32N (bf16 rows)
    unsigned int* hpp  = (unsigned int*)(wsb + ((size_t)41 * N + 13312 + 2 * (size_t)E) * 4);       // 32N (hbf, then ppbf)

    // zero only the histogram accumulators
    hipMemsetAsync(wsb, 0, (size_t)2 * N * 4, stream);

    hist_kernel <<<(E + 255) / 256, 256, 0, stream>>>(ei, E, degS, cnt);
    dinv_kernel <<<NB, 256, 0, stream>>>(degS, dinv, N);

    // CSR build (srcs sorted by dst, weight = dinv[src] fused in)
    scanA_kernel<<<NB, 256, 0, stream>>>(cnt, bs, N);
    scanB_kernel<<<1, 1024, 0, stream>>>(bs, NB);
    scanC_kernel<<<NB, 256, 0, stream>>>(cnt, bs, row, cur, N);
    fill_kernel <<<(E + 255) / 256, 256, 0, stream>>>(ei, E, dinv, cur, srcw);

    w2eff_kernel<<<(192 * 64 + 255) / 256, 256, 0, stream>>>(W2, W2e);
    packh_kernel<<<(32 * N + 255) / 256, 256, 0, stream>>>(h, hpp, 32 * N);

    // input path: x -> txa -> txb (2 channels, gather)
    gather2_kernel<<<NB, 256, 0, stream>>>(row, cnt, srcw, dinv, x,   txa, N);
    gather2_kernel<<<NB, 256, 0, stream>>>(row, cnt, srcw, dinv, txa, txb, N);

    // hidden path: hbf -> bufA -> ppbf (bf16 rows; hpp reused as dst of pass 2)
    int gblocks = (N + 3) / 4;
    gather64_kernel<<<gblocks, 256, 0, stream>>>(row, cnt, srcw, dinv, hpp,  bufA, N);
    gather64_kernel<<<gblocks, 256, 0, stream>>>(row, cnt, srcw, dinv, bufA, hpp,  N);

    // fused input_conv + hidden_conv + gates (persistent, 4 blocks/CU)
    int T = (N + 63) / 64;
    int gateblocks = T < 1024 ? T : 1024;
    gate_fused_kernel<<<gateblocks, 256, 0, stream>>>(
        out, x, h, txa, txb, bufA, hpp, W1, b1, W2e, b2, Wz, bz, Wr, br, Wc, bc, N);
}